// Round 6
// baseline (96.759 us; speedup 1.0000x reference)
//
#include <hip/hip_runtime.h>

#define IMG   256
#define SROWS 32    // output rows per block (strip)
#define KS    29
#define PAD   14
#define LDSS  292   // LDS row stride in floats (mult of 4 for alignment; halo 2..15 + main 16..271 + halo 272..285)
#define MOFF  16    // main-data float offset inside an LDS row (layout offset = padded position + 2)

// exp(-d^2/(2*49)) for d=0..14; normalization folds at compile time.
static constexpr float GK[15] = {
    1.0f,        0.98984780f, 0.96000544f, 0.91225408f, 0.84936581f,
    0.77483743f, 0.69256933f, 0.60653066f, 0.52045012f, 0.43756474f,
    0.36044779f, 0.29092381f, 0.23006630f, 0.17826398f, 0.13533528f
};
static constexpr float GSUM =
    GK[0] + 2.0f * (GK[1] + GK[2] + GK[3] + GK[4] + GK[5] + GK[6] + GK[7] +
                    GK[8] + GK[9] + GK[10] + GK[11] + GK[12] + GK[13] + GK[14]);
static constexpr float WT[29] = {
    GK[14]/GSUM, GK[13]/GSUM, GK[12]/GSUM, GK[11]/GSUM, GK[10]/GSUM, GK[9]/GSUM, GK[8]/GSUM,
    GK[7]/GSUM,  GK[6]/GSUM,  GK[5]/GSUM,  GK[4]/GSUM,  GK[3]/GSUM,  GK[2]/GSUM, GK[1]/GSUM,
    GK[0]/GSUM,
    GK[1]/GSUM,  GK[2]/GSUM,  GK[3]/GSUM,  GK[4]/GSUM,  GK[5]/GSUM,  GK[6]/GSUM, GK[7]/GSUM,
    GK[8]/GSUM,  GK[9]/GSUM,  GK[10]/GSUM, GK[11]/GSUM, GK[12]/GSUM, GK[13]/GSUM, GK[14]/GSUM
};

__device__ __forceinline__ int refl(int p) {
    int a = p < 0 ? -p : p;        // reflect at 0
    int b = 2 * (IMG - 1) - a;     // reflect at 255
    return a < b ? a : b;
}

__global__ __launch_bounds__(256, 4)   // 128-VGPR budget: deep load ILP
void gauss_v6(const float* __restrict__ x, float* __restrict__ out) {
    __shared__ float s[SROWS * LDSS];  // 37,376 B -> 4 blocks/CU by LDS

    const int t   = threadIdx.x;
    const int img = blockIdx.y;
    const int y0  = blockIdx.x * SROWS;

    const float* __restrict__ src = x   + (size_t)img * (IMG * IMG);
    float*       __restrict__ dst = out + (size_t)img * (IMG * IMG);

    const int cq = t & 63;      // col quad 0..63 (lane id -> coalesced)
    const int rg = t >> 6;      // row group 0..3, wave-uniform
    const int c0 = cq * 4;

    // ---- Phase A: vertical conv. Each thread: 8 output rows x 4 cols.
    //      Window = 36 input rows, loaded as 3 chunks of 12 independent float4s.
    {
        const int brow = y0 + rg * 8 - PAD;

        float4 acc[8];
        #pragma unroll
        for (int j = 0; j < 8; ++j) acc[j] = make_float4(0.f, 0.f, 0.f, 0.f);

        const bool interior = (brow >= 0) && (brow + 35 < IMG);
        if (interior) {
            const float* p = src + (size_t)brow * IMG + c0;
            #pragma unroll
            for (int ch = 0; ch < 3; ++ch) {
                float4 v[12];
                #pragma unroll
                for (int i = 0; i < 12; ++i)
                    v[i] = *(const float4*)(p + (ch * 12 + i) * IMG);
                #pragma unroll
                for (int i = 0; i < 12; ++i) {
                    const int sdx = ch * 12 + i;
                    #pragma unroll
                    for (int j = 0; j < 8; ++j) {
                        const int k = sdx - j;
                        if (k >= 0 && k < KS) {
                            acc[j].x += WT[k] * v[i].x;
                            acc[j].y += WT[k] * v[i].y;
                            acc[j].z += WT[k] * v[i].z;
                            acc[j].w += WT[k] * v[i].w;
                        }
                    }
                }
            }
        } else {
            #pragma unroll
            for (int ch = 0; ch < 3; ++ch) {
                float4 v[12];
                #pragma unroll
                for (int i = 0; i < 12; ++i)
                    v[i] = *(const float4*)(src + (size_t)refl(brow + ch * 12 + i) * IMG + c0);
                #pragma unroll
                for (int i = 0; i < 12; ++i) {
                    const int sdx = ch * 12 + i;
                    #pragma unroll
                    for (int j = 0; j < 8; ++j) {
                        const int k = sdx - j;
                        if (k >= 0 && k < KS) {
                            acc[j].x += WT[k] * v[i].x;
                            acc[j].y += WT[k] * v[i].y;
                            acc[j].z += WT[k] * v[i].z;
                            acc[j].w += WT[k] * v[i].w;
                        }
                    }
                }
            }
        }

        // aligned b128 stores, lane-consecutive -> conflict-free
        #pragma unroll
        for (int j = 0; j < 8; ++j)
            *(float4*)&s[(rg * 8 + j) * LDSS + MOFF + c0] = acc[j];

        // mirrored horizontal halo (reflect-101); only edge quads enter.
        // layout offset = padded position + 2:
        //   left  : col c (1..14)    -> padded pos 14-c  -> offset MOFF - c          (2..15)
        //   right : col c (241..254) -> padded pos 524-c -> offset MOFF + 510 - c    (272..285)
        if (c0 <= PAD || c0 + 3 >= IMG - 1 - PAD) {
            #pragma unroll
            for (int q = 0; q < 4; ++q) {
                const int c = c0 + q;
                if (c >= 1 && c <= PAD) {
                    #pragma unroll
                    for (int j = 0; j < 8; ++j) {
                        const float v = q == 0 ? acc[j].x : q == 1 ? acc[j].y : q == 2 ? acc[j].z : acc[j].w;
                        s[(rg * 8 + j) * LDSS + (MOFF - c)] = v;
                    }
                } else if (c >= IMG - 1 - PAD && c <= IMG - 2) {
                    #pragma unroll
                    for (int j = 0; j < 8; ++j) {
                        const float v = q == 0 ? acc[j].x : q == 1 ? acc[j].y : q == 2 ? acc[j].z : acc[j].w;
                        s[(rg * 8 + j) * LDSS + (MOFF + 2 * (IMG - 1) - c)] = v;
                    }
                }
            }
        }
    }
    __syncthreads();

    // ---- Phase B: horizontal conv. Same (col-quad, row-group) mapping ->
    //      coalesced float4 global stores. 9 aligned b128 LDS reads per row.
    //      Read window starts at float offset c0 (= padded pos c0-2); tap for
    //      output col c0+c from element p is k = p - c - 2.
    {
        #pragma unroll
        for (int r = 0; r < 8; ++r) {
            const int row = rg * 8 + r;
            const float4* w = (const float4*)&s[row * LDSS + c0];
            float4 v[9];
            #pragma unroll
            for (int m = 0; m < 9; ++m) v[m] = w[m];

            float4 o = make_float4(0.f, 0.f, 0.f, 0.f);
            #pragma unroll
            for (int m = 0; m < 9; ++m) {
                #pragma unroll
                for (int q = 0; q < 4; ++q) {
                    const int p = 4 * m + q;
                    const float val = q == 0 ? v[m].x : q == 1 ? v[m].y : q == 2 ? v[m].z : v[m].w;
                    #pragma unroll
                    for (int c = 0; c < 4; ++c) {
                        const int k = p - c - 2;
                        if (k >= 0 && k < KS) {
                            if (c == 0) o.x += WT[k] * val;
                            else if (c == 1) o.y += WT[k] * val;
                            else if (c == 2) o.z += WT[k] * val;
                            else o.w += WT[k] * val;
                        }
                    }
                }
            }
            *(float4*)&dst[(size_t)(y0 + row) * IMG + c0] = o;   // lane-contiguous 1KB line
        }
    }
}

extern "C" void kernel_launch(void* const* d_in, const int* in_sizes, int n_in,
                              void* d_out, int out_size, void* d_ws, size_t ws_size,
                              hipStream_t stream) {
    const float* x = (const float*)d_in[0];
    float* out = (float*)d_out;
    const int images = in_sizes[0] / (IMG * IMG);   // 8*64 = 512
    dim3 grid(IMG / SROWS, images);                 // (8, 512)
    gauss_v6<<<grid, dim3(256), 0, stream>>>(x, out);
}